// Round 4
// baseline (879.694 us; speedup 1.0000x reference)
//
#include <hip/hip_runtime.h>
#include <stdint.h>

typedef short short8 __attribute__((ext_vector_type(8)));
typedef _Float16 half4 __attribute__((ext_vector_type(4)));
typedef float floatx4 __attribute__((ext_vector_type(4)));

#define LOG2E 1.44269504088896340736f
#define QSCALE (0.125f * LOG2E)   // SCALE * log2(e), folded into Q

static __device__ __forceinline__ unsigned short f2bf(float f) {
  unsigned int u = __float_as_uint(f);
  u += 0x7fffu + ((u >> 16) & 1u);
  return (unsigned short)(u >> 16);
}

static __device__ __forceinline__ float fexp2(float x) {
#if __has_builtin(__builtin_amdgcn_exp2f)
  return __builtin_amdgcn_exp2f(x);
#else
  return exp2f(x);
#endif
}

#define GLD_LDS16(gp, lp)                                                      \
  __builtin_amdgcn_global_load_lds(                                            \
      (const __attribute__((address_space(1))) void*)(gp),                     \
      (__attribute__((address_space(3))) void*)(lp), 16, 0, 0)

// ---------------------------------------------------------------- convert
__global__ __launch_bounds__(256) void cvt_f32_bf16(
    const float* __restrict__ in, unsigned short* __restrict__ out, int n) {
  int i = (blockIdx.x * 256 + threadIdx.x) * 4;
  if (i >= n) return;
  float4 v = *(const float4*)(in + i);
  ushort4 u;
  u.x = f2bf(v.x); u.y = f2bf(v.y); u.z = f2bf(v.z); u.w = f2bf(v.w);
  *(ushort4*)(out + i) = u;
}

// ---------------------------------------------------------------- GEMM
// C[M,N] = A[M,K] @ B[N,K]^T + bias   (A,B bf16 row-major, K contiguous)
// MODE 0: write fp32 C to outF.
// MODE 1: qkv epilogue -> q(*QSCALE)[B,h,T,d] bf16, k[B,h,T,d] bf16,
//         vT[B,h,d,T] as f16.
template <int MODE>
__global__ __launch_bounds__(256, 2) void gemm_bt(
    const unsigned short* __restrict__ A, const unsigned short* __restrict__ Bm,
    const float* __restrict__ bias, float* __restrict__ outF,
    unsigned short* __restrict__ qo, unsigned short* __restrict__ ko,
    _Float16* __restrict__ vto, int M, int N, int K) {
  __shared__ unsigned short As[128 * 64];
  __shared__ unsigned short Bs[128 * 64];
  const int tid = threadIdx.x;
  const int w = tid >> 6, l = tid & 63;
  const int lr = l & 15, lg = l >> 4;
  const int nbn = N >> 7;
  const int nwg = gridDim.x;
  const int bid = blockIdx.x;
  const int cpx = nwg >> 3;
  const int swz = (bid & 7) * cpx + (bid >> 3);
  const int bm = swz / nbn, bn = swz % nbn;
  const int wm = w >> 1, wn = w & 1;

  floatx4 acc[4][4];
#pragma unroll
  for (int i = 0; i < 4; ++i)
#pragma unroll
    for (int j = 0; j < 4; ++j) acc[i][j] = (floatx4){0.f, 0.f, 0.f, 0.f};

  for (int k0 = 0; k0 < K; k0 += 64) {
#pragma unroll
    for (int i = 0; i < 4; ++i) {
      int c = i * 256 + tid;
      const unsigned short* ga =
          A + ((size_t)bm * 128 + (c >> 3)) * K + k0 + (c & 7) * 8;
      GLD_LDS16(ga, As + (size_t)(i * 256 + w * 64) * 8);
    }
#pragma unroll
    for (int i = 0; i < 4; ++i) {
      int c = i * 256 + tid;
      const unsigned short* gb =
          Bm + ((size_t)bn * 128 + (c >> 3)) * K + k0 + (c & 7) * 8;
      GLD_LDS16(gb, Bs + (size_t)(i * 256 + w * 64) * 8);
    }
    __syncthreads();
#pragma unroll
    for (int kk = 0; kk < 2; ++kk) {
      short8 af[4], bf[4];
#pragma unroll
      for (int i = 0; i < 4; ++i)
        af[i] = *(const short8*)&As[(wm * 64 + i * 16 + lr) * 64 + kk * 32 + lg * 8];
#pragma unroll
      for (int j = 0; j < 4; ++j)
        bf[j] = *(const short8*)&Bs[(wn * 64 + j * 16 + lr) * 64 + kk * 32 + lg * 8];
#pragma unroll
      for (int i = 0; i < 4; ++i)
#pragma unroll
        for (int j = 0; j < 4; ++j)
          acc[i][j] = __builtin_amdgcn_mfma_f32_16x16x32_bf16(af[i], bf[j],
                                                              acc[i][j], 0, 0, 0);
    }
    __syncthreads();
  }

#pragma unroll
  for (int i = 0; i < 4; ++i) {
    int row0 = bm * 128 + wm * 64 + i * 16 + lg * 4;
#pragma unroll
    for (int j = 0; j < 4; ++j) {
      int col = bn * 128 + wn * 64 + j * 16 + lr;
      float bv = bias[col];
#pragma unroll
      for (int jj = 0; jj < 4; ++jj) {
        float v = acc[i][j][jj] + bv;
        int r = row0 + jj;
        if (MODE == 0) {
          outF[(size_t)r * N + col] = v;
        } else {
          int three = col >> 10, cc = col & 1023;
          int h = cc >> 6, d = cc & 63;
          int b = r >> 11, t = r & 2047;
          if (three == 0)
            qo[(((size_t)(b * 16 + h)) * 2048 + t) * 64 + d] = f2bf(v * QSCALE);
          else if (three == 1)
            ko[(((size_t)(b * 16 + h)) * 2048 + t) * 64 + d] = f2bf(v);
          else
            vto[(((size_t)(b * 16 + h)) * 64 + d) * 2048 + t] = (_Float16)v;
        }
      }
    }
  }
}

// ---------------------------------------------------------------- attention
// Swapped-QK flash attention on the 16x16 MFMA family ONLY (all layouts
// verified in-harness by round 1):
//   S^T tile  = mfma_f32_16x16x32_bf16(A=K_rows, B=Q_rows):
//       lane(l4,g) reg jj holds S^T[kv=f*16+g*4+jj][q=l4]   (q = col domain)
//   P A-frag for mfma_f32_16x16x16f16 needs k = g*4+j  -> EXACTLY the 4
//       in-lane consecutive kv the S^T layout provides: no shuffles, no LDS.
//   PV: O = mfma_16x16x16_f16(A=P[q x kv16], B=V[kv16 x dv]): out row =
//       g*4+jj = q (row domain), col = l4 = dv.
// Softmax scalars live in q=l4 (col) domain; crossing to the row domain
// happens only for the O rescale and the epilogue, via __shfl(., g*4+jj).
// grid 2048 = 64 bh x 32 q-tiles; block 256 = 4 waves x 16 q-rows.
__global__ __launch_bounds__(256, 3) void attn_fwd(
    const unsigned short* __restrict__ Qg, const unsigned short* __restrict__ Kg,
    const _Float16* __restrict__ VTg, unsigned short* __restrict__ Og) {
  const int bid0 = blockIdx.x;
  const int bid = (bid0 & 7) * 256 + (bid0 >> 3);  // 8 bh per XCD (K/V = 4MB ~ L2)
  const int bh = bid >> 5, qt = bid & 31;
  const int b = bh >> 4, hh = bh & 15;
  const int tid = threadIdx.x, w = tid >> 6, l = tid & 63;
  const int l4 = l & 15, g = l >> 4;
  const unsigned short* Q = Qg + (size_t)bh * (2048 * 64);
  const unsigned short* Kp = Kg + (size_t)bh * (2048 * 64);
  const _Float16* VT = VTg + (size_t)bh * (64 * 2048);
  const int q0 = qt * 64 + w * 16;

  // Q B-frag (col = l4 = q, k = c*32 + g*8 + j), contiguous 16B
  short8 qf[2];
#pragma unroll
  for (int c = 0; c < 2; ++c)
    qf[c] = *(const short8*)&Q[(size_t)(q0 + l4) * 64 + c * 32 + g * 8];

  floatx4 o[4];
#pragma unroll
  for (int db = 0; db < 4; ++db) o[db] = (floatx4){0.f, 0.f, 0.f, 0.f};
  float m = -__builtin_inff(), lsum = 0.f;

  for (int t0 = 0; t0 < 2048; t0 += 64) {
    // ---- S^T[f] = K_f @ Q^T  (f = 16-row kv subtile)
    floatx4 s[4];
#pragma unroll
    for (int f = 0; f < 4; ++f) {
      s[f] = (floatx4){0.f, 0.f, 0.f, 0.f};
      const unsigned short* kr = &Kp[(size_t)(t0 + f * 16 + l4) * 64 + g * 8];
      short8 kf0 = *(const short8*)kr;
      short8 kf1 = *(const short8*)(kr + 32);
      s[f] = __builtin_amdgcn_mfma_f32_16x16x32_bf16(kf0, qf[0], s[f], 0, 0, 0);
      s[f] = __builtin_amdgcn_mfma_f32_16x16x32_bf16(kf1, qf[1], s[f], 0, 0, 0);
    }

    // ---- V B-frags (f16, 8B each) prefetched before softmax
    half4 vf[4][4];
#pragma unroll
    for (int db = 0; db < 4; ++db)
#pragma unroll
      for (int f = 0; f < 4; ++f)
        vf[db][f] = *(const half4*)&VT[(size_t)(db * 16 + l4) * 2048 + t0 + f * 16 + g * 4];

    // ---- online softmax (log2 domain), per-lane q = l4
    float a0 = fmaxf(fmaxf(s[0][0], s[0][1]), fmaxf(s[0][2], s[0][3]));
    float a1 = fmaxf(fmaxf(s[1][0], s[1][1]), fmaxf(s[1][2], s[1][3]));
    float a2 = fmaxf(fmaxf(s[2][0], s[2][1]), fmaxf(s[2][2], s[2][3]));
    float a3 = fmaxf(fmaxf(s[3][0], s[3][1]), fmaxf(s[3][2], s[3][3]));
    float pm = fmaxf(fmaxf(a0, a1), fmaxf(a2, a3));
    pm = fmaxf(pm, __shfl_xor(pm, 16));
    pm = fmaxf(pm, __shfl_xor(pm, 32));

    if (!__all(pm - m <= 8.0f)) {  // defer-max: P bounded by 2^8 (exact for any m)
      float mo = m;
      m = fmaxf(m, pm);
      float al = fexp2(mo - m);
      lsum *= al;
      // o rows are q = g*4+jj (row domain); al lives at q = l4 -> shfl.
#pragma unroll
      for (int jj = 0; jj < 4; ++jj) {
        float alr = __shfl(al, g * 4 + jj);
        o[0][jj] *= alr; o[1][jj] *= alr; o[2][jj] *= alr; o[3][jj] *= alr;
      }
    }

    // ---- P = 2^(S-m); A-frag is the lane's own 4 consecutive kv -> no shuffle
    half4 pf[4];
    float rs = 0.f;
#pragma unroll
    for (int f = 0; f < 4; ++f) {
      float p0 = fexp2(s[f][0] - m), p1 = fexp2(s[f][1] - m);
      float p2 = fexp2(s[f][2] - m), p3 = fexp2(s[f][3] - m);
      rs += (p0 + p1) + (p2 + p3);
      half4 ph;
      ph[0] = (_Float16)p0; ph[1] = (_Float16)p1;
      ph[2] = (_Float16)p2; ph[3] = (_Float16)p3;
      pf[f] = ph;
    }
    rs += __shfl_xor(rs, 16);
    rs += __shfl_xor(rs, 32);
    lsum += rs;

    // ---- O += P @ V  (16x16x16 f16, K=16 per f-subtile)
#pragma unroll
    for (int db = 0; db < 4; ++db)
#pragma unroll
      for (int f = 0; f < 4; ++f)
        o[db] = __builtin_amdgcn_mfma_f32_16x16x16f16(pf[f], vf[db][f], o[db], 0, 0, 0);
  }

  // ---- epilogue: out[b, q0 + g*4+jj, hh*64 + db*16 + l4]
  float invq = 1.f / lsum;
  float inv[4];
#pragma unroll
  for (int jj = 0; jj < 4; ++jj) inv[jj] = __shfl(invq, g * 4 + jj);
#pragma unroll
  for (int db = 0; db < 4; ++db)
#pragma unroll
    for (int jj = 0; jj < 4; ++jj)
      Og[((size_t)b * 2048 + q0 + g * 4 + jj) * 1024 + hh * 64 + db * 16 + l4] =
          f2bf(o[db][jj] * inv[jj]);
}

// ---------------------------------------------------------------- launch
extern "C" void kernel_launch(void* const* d_in, const int* in_sizes, int n_in,
                              void* d_out, int out_size, void* d_ws, size_t ws_size,
                              hipStream_t stream) {
  const float* x = (const float*)d_in[0];
  const float* w_qkv = (const float*)d_in[1];
  const float* b_qkv = (const float*)d_in[2];
  const float* w_proj = (const float*)d_in[3];
  const float* b_proj = (const float*)d_in[4];
  float* out = (float*)d_out;

  char* p = (char*)d_ws;
  unsigned short* xb = (unsigned short*)p;     p += (size_t)8192 * 1024 * 2;
  unsigned short* wqkvb = (unsigned short*)p;  p += (size_t)3072 * 1024 * 2;
  unsigned short* wprojb = (unsigned short*)p; p += (size_t)1024 * 1024 * 2;
  unsigned short* qb = (unsigned short*)p;     p += (size_t)64 * 2048 * 64 * 2;
  unsigned short* kb = (unsigned short*)p;     p += (size_t)64 * 2048 * 64 * 2;
  _Float16* vtb = (_Float16*)p;                p += (size_t)64 * 64 * 2048 * 2;
  unsigned short* attnb = (unsigned short*)p;  p += (size_t)8192 * 1024 * 2;

  cvt_f32_bf16<<<dim3(8192), dim3(256), 0, stream>>>(x, xb, 8192 * 1024);
  cvt_f32_bf16<<<dim3(3072), dim3(256), 0, stream>>>(w_qkv, wqkvb, 3072 * 1024);
  cvt_f32_bf16<<<dim3(1024), dim3(256), 0, stream>>>(w_proj, wprojb, 1024 * 1024);

  gemm_bt<1><<<dim3(64 * 24), dim3(256), 0, stream>>>(
      xb, wqkvb, b_qkv, nullptr, qb, kb, vtb, 8192, 3072, 1024);

  attn_fwd<<<dim3(2048), dim3(256), 0, stream>>>(qb, kb, vtb, attnb);

  gemm_bt<0><<<dim3(64 * 8), dim3(256), 0, stream>>>(
      attnb, wprojb, b_proj, out, nullptr, nullptr, nullptr, 8192, 1024, 1024);
}

// Round 5
// 228.917 us; speedup vs baseline: 3.8429x; 3.8429x over previous
//
#include <hip/hip_runtime.h>
#include <stdint.h>

typedef short short8 __attribute__((ext_vector_type(8)));
typedef _Float16 half4 __attribute__((ext_vector_type(4)));
typedef float floatx4 __attribute__((ext_vector_type(4)));

#define LOG2E 1.44269504088896340736f
#define QSCALE (0.125f * LOG2E)   // SCALE * log2(e), folded into Q

static __device__ __forceinline__ unsigned short f2bf(float f) {
  unsigned int u = __float_as_uint(f);
  u += 0x7fffu + ((u >> 16) & 1u);
  return (unsigned short)(u >> 16);
}

static __device__ __forceinline__ float fexp2(float x) {
#if __has_builtin(__builtin_amdgcn_exp2f)
  return __builtin_amdgcn_exp2f(x);
#else
  return exp2f(x);
#endif
}

#define GLD_LDS16(gp, lp)                                                      \
  __builtin_amdgcn_global_load_lds(                                            \
      (const __attribute__((address_space(1))) void*)(gp),                     \
      (__attribute__((address_space(3))) void*)(lp), 16, 0, 0)

// ---------------------------------------------------------------- convert
__global__ __launch_bounds__(256) void cvt_f32_bf16(
    const float* __restrict__ in, unsigned short* __restrict__ out, int n) {
  int i = (blockIdx.x * 256 + threadIdx.x) * 4;
  if (i >= n) return;
  float4 v = *(const float4*)(in + i);
  ushort4 u;
  u.x = f2bf(v.x); u.y = f2bf(v.y); u.z = f2bf(v.z); u.w = f2bf(v.w);
  *(ushort4*)(out + i) = u;
}

// ---------------------------------------------------------------- GEMM
// C[M,N] = A[M,K] @ B[N,K]^T + bias   (A,B bf16 row-major, K contiguous)
// MODE 0: write fp32 C to outF.
// MODE 1: qkv epilogue -> q(*QSCALE)[B,h,T,d] bf16, k[B,h,T,d] bf16,
//         vT[B,h,d,T] as f16.
template <int MODE>
__global__ __launch_bounds__(256, 2) void gemm_bt(
    const unsigned short* __restrict__ A, const unsigned short* __restrict__ Bm,
    const float* __restrict__ bias, float* __restrict__ outF,
    unsigned short* __restrict__ qo, unsigned short* __restrict__ ko,
    _Float16* __restrict__ vto, int M, int N, int K) {
  __shared__ unsigned short As[128 * 64];
  __shared__ unsigned short Bs[128 * 64];
  const int tid = threadIdx.x;
  const int w = tid >> 6, l = tid & 63;
  const int lr = l & 15, lg = l >> 4;
  const int nbn = N >> 7;
  const int nwg = gridDim.x;
  const int bid = blockIdx.x;
  const int cpx = nwg >> 3;
  const int swz = (bid & 7) * cpx + (bid >> 3);
  const int bm = swz / nbn, bn = swz % nbn;
  const int wm = w >> 1, wn = w & 1;

  floatx4 acc[4][4];
#pragma unroll
  for (int i = 0; i < 4; ++i)
#pragma unroll
    for (int j = 0; j < 4; ++j) acc[i][j] = (floatx4){0.f, 0.f, 0.f, 0.f};

  for (int k0 = 0; k0 < K; k0 += 64) {
#pragma unroll
    for (int i = 0; i < 4; ++i) {
      int c = i * 256 + tid;
      const unsigned short* ga =
          A + ((size_t)bm * 128 + (c >> 3)) * K + k0 + (c & 7) * 8;
      GLD_LDS16(ga, As + (size_t)(i * 256 + w * 64) * 8);
    }
#pragma unroll
    for (int i = 0; i < 4; ++i) {
      int c = i * 256 + tid;
      const unsigned short* gb =
          Bm + ((size_t)bn * 128 + (c >> 3)) * K + k0 + (c & 7) * 8;
      GLD_LDS16(gb, Bs + (size_t)(i * 256 + w * 64) * 8);
    }
    __syncthreads();
#pragma unroll
    for (int kk = 0; kk < 2; ++kk) {
      short8 af[4], bf[4];
#pragma unroll
      for (int i = 0; i < 4; ++i)
        af[i] = *(const short8*)&As[(wm * 64 + i * 16 + lr) * 64 + kk * 32 + lg * 8];
#pragma unroll
      for (int j = 0; j < 4; ++j)
        bf[j] = *(const short8*)&Bs[(wn * 64 + j * 16 + lr) * 64 + kk * 32 + lg * 8];
#pragma unroll
      for (int i = 0; i < 4; ++i)
#pragma unroll
        for (int j = 0; j < 4; ++j)
          acc[i][j] = __builtin_amdgcn_mfma_f32_16x16x32_bf16(af[i], bf[j],
                                                              acc[i][j], 0, 0, 0);
    }
    __syncthreads();
  }

#pragma unroll
  for (int i = 0; i < 4; ++i) {
    int row0 = bm * 128 + wm * 64 + i * 16 + lg * 4;
#pragma unroll
    for (int j = 0; j < 4; ++j) {
      int col = bn * 128 + wn * 64 + j * 16 + lr;
      float bv = bias[col];
#pragma unroll
      for (int jj = 0; jj < 4; ++jj) {
        float v = acc[i][j][jj] + bv;
        int r = row0 + jj;
        if (MODE == 0) {
          outF[(size_t)r * N + col] = v;
        } else {
          int three = col >> 10, cc = col & 1023;
          int h = cc >> 6, d = cc & 63;
          int b = r >> 11, t = r & 2047;
          if (three == 0)
            qo[(((size_t)(b * 16 + h)) * 2048 + t) * 64 + d] = f2bf(v * QSCALE);
          else if (three == 1)
            ko[(((size_t)(b * 16 + h)) * 2048 + t) * 64 + d] = f2bf(v);
          else
            vto[(((size_t)(b * 16 + h)) * 64 + d) * 2048 + t] = (_Float16)v;
        }
      }
    }
  }
}

// ---------------------------------------------------------------- attention
// Same verified math/layouts as round 4 (16x16 MFMA family only, swapped QK):
//   S^T = mfma_16x16x32_bf16(A=K_rows, B=Q_rows): lane(l4,g) reg jj holds
//     S^T[kv=f*16+g*4+jj][q=l4]  (q = col domain)
//   P A-frag for mfma_16x16x16f16: k=g*4+j == lane's own 4 consecutive kv.
//   PV out: row = g*4+jj = q (row domain), col = l4 = dv.
// NEW: K (bf16) and V^T (f16) tiles staged in double-buffered LDS via
// global_load_lds (coalesced), 16B-granular XOR swizzle applied on the
// GLOBAL source address (LDS dest must stay linear) and matching XOR on
// the LDS read side. 4 waves x 32 q (two 16-q subtiles sharing all K/V
// fragments). grid 1024 = 64 bh x 16 q-tiles.
__global__ __launch_bounds__(256, 3) void attn_fwd(
    const unsigned short* __restrict__ Qg, const unsigned short* __restrict__ Kg,
    const _Float16* __restrict__ VTg, unsigned short* __restrict__ Og) {
  __shared__ unsigned short Ks[2][64 * 64];
  __shared__ _Float16 Vs[2][64 * 64];

  const int bid0 = blockIdx.x;
  const int bid = (bid0 & 7) * 128 + (bid0 >> 3);  // 8 bh per XCD (K/V=4MB ~ L2)
  const int bh = bid >> 4, qt = bid & 15;
  const int b = bh >> 4, hh = bh & 15;
  const int tid = threadIdx.x, w = tid >> 6, l = tid & 63;
  const int l4 = l & 15, g = l >> 4;
  const unsigned short* Q = Qg + (size_t)bh * (2048 * 64);
  const unsigned short* Kp = Kg + (size_t)bh * (2048 * 64);
  const _Float16* VT = VTg + (size_t)bh * (64 * 2048);
  const int qw = qt * 128 + w * 32;

// stage K tile [64 kv][64 d] bf16 and V^T tile [64 dv][64 kv] f16 into LDS.
// chunk c (0..511): row=c>>3, slot16=c&7; source slot XOR'd so linear LDS
// dest receives the swizzled layout (rule #21: swizzle both sides).
#define STAGE(bufidx, tt)                                                     \
  do {                                                                        \
    int c0 = tid, c1 = 256 + tid;                                             \
    int r0 = c0 >> 3, s0 = (c0 & 7) ^ (r0 & 7);                               \
    int r1 = c1 >> 3, s1 = (c1 & 7) ^ (r1 & 7);                               \
    GLD_LDS16(Kp + (size_t)((tt) + r0) * 64 + s0 * 8, &Ks[bufidx][c0 * 8]);   \
    GLD_LDS16(Kp + (size_t)((tt) + r1) * 64 + s1 * 8, &Ks[bufidx][c1 * 8]);   \
    GLD_LDS16(VT + (size_t)r0 * 2048 + (tt) + s0 * 8, &Vs[bufidx][c0 * 8]);   \
    GLD_LDS16(VT + (size_t)r1 * 2048 + (tt) + s1 * 8, &Vs[bufidx][c1 * 8]);   \
  } while (0)

  // Q B-frags for two 16-q subtiles (col = l4 = q, k = c*32 + g*8 + j)
  short8 qf[2][2];
#pragma unroll
  for (int qs = 0; qs < 2; ++qs)
#pragma unroll
    for (int c = 0; c < 2; ++c)
      qf[qs][c] =
          *(const short8*)&Q[(size_t)(qw + qs * 16 + l4) * 64 + c * 32 + g * 8];

  floatx4 o[2][4];
#pragma unroll
  for (int qs = 0; qs < 2; ++qs)
#pragma unroll
    for (int db = 0; db < 4; ++db) o[qs][db] = (floatx4){0.f, 0.f, 0.f, 0.f};
  float m[2] = {-__builtin_inff(), -__builtin_inff()};
  float lsum[2] = {0.f, 0.f};

  STAGE(0, 0);
  __syncthreads();

  for (int it = 0; it < 32; ++it) {
    const int cur = it & 1;
    if (it + 1 < 32) STAGE(cur ^ 1, (it + 1) * 64);

    // ---- S^T[qs][f] = K_f @ Q^T ; K frags shared across both q-subtiles
    floatx4 s[2][4];
#pragma unroll
    for (int f = 0; f < 4; ++f) {
      short8 kf0 = *(const short8*)&Ks[cur][(f * 16 + l4) * 64 +
                                            ((g ^ (l4 & 7)) * 8)];
      short8 kf1 = *(const short8*)&Ks[cur][(f * 16 + l4) * 64 +
                                            (((4 + g) ^ (l4 & 7)) * 8)];
      floatx4 z = (floatx4){0.f, 0.f, 0.f, 0.f};
      floatx4 t00 = __builtin_amdgcn_mfma_f32_16x16x32_bf16(kf0, qf[0][0], z, 0, 0, 0);
      s[0][f] = __builtin_amdgcn_mfma_f32_16x16x32_bf16(kf1, qf[0][1], t00, 0, 0, 0);
      floatx4 t10 = __builtin_amdgcn_mfma_f32_16x16x32_bf16(kf0, qf[1][0], z, 0, 0, 0);
      s[1][f] = __builtin_amdgcn_mfma_f32_16x16x32_bf16(kf1, qf[1][1], t10, 0, 0, 0);
    }

    // ---- online softmax per subtile (log2 domain, q = l4 col domain)
    half4 pf[2][4];
#pragma unroll
    for (int qs = 0; qs < 2; ++qs) {
      float a0 = fmaxf(fmaxf(s[qs][0][0], s[qs][0][1]), fmaxf(s[qs][0][2], s[qs][0][3]));
      float a1 = fmaxf(fmaxf(s[qs][1][0], s[qs][1][1]), fmaxf(s[qs][1][2], s[qs][1][3]));
      float a2 = fmaxf(fmaxf(s[qs][2][0], s[qs][2][1]), fmaxf(s[qs][2][2], s[qs][2][3]));
      float a3 = fmaxf(fmaxf(s[qs][3][0], s[qs][3][1]), fmaxf(s[qs][3][2], s[qs][3][3]));
      float pm = fmaxf(fmaxf(a0, a1), fmaxf(a2, a3));
      pm = fmaxf(pm, __shfl_xor(pm, 16));
      pm = fmaxf(pm, __shfl_xor(pm, 32));

      if (!__all(pm - m[qs] <= 8.0f)) {  // defer-max: P bounded by 2^8
        float mo = m[qs];
        m[qs] = fmaxf(m[qs], pm);
        float al = fexp2(mo - m[qs]);
        lsum[qs] *= al;
        // o rows are q = g*4+jj (row domain); al lives at q = l4 -> shfl.
#pragma unroll
        for (int jj = 0; jj < 4; ++jj) {
          float alr = __shfl(al, g * 4 + jj);
          o[qs][0][jj] *= alr; o[qs][1][jj] *= alr;
          o[qs][2][jj] *= alr; o[qs][3][jj] *= alr;
        }
      }

      float rs = 0.f;
#pragma unroll
      for (int f = 0; f < 4; ++f) {
        float p0 = fexp2(s[qs][f][0] - m[qs]), p1 = fexp2(s[qs][f][1] - m[qs]);
        float p2 = fexp2(s[qs][f][2] - m[qs]), p3 = fexp2(s[qs][f][3] - m[qs]);
        rs += (p0 + p1) + (p2 + p3);
        half4 ph;
        ph[0] = (_Float16)p0; ph[1] = (_Float16)p1;
        ph[2] = (_Float16)p2; ph[3] = (_Float16)p3;
        pf[qs][f] = ph;
      }
      rs += __shfl_xor(rs, 16);
      rs += __shfl_xor(rs, 32);
      lsum[qs] += rs;
    }

    // ---- O += P @ V ; V frags shared across both q-subtiles
#pragma unroll
    for (int db = 0; db < 4; ++db) {
#pragma unroll
      for (int f = 0; f < 4; ++f) {
        half4 vf = *(const half4*)&Vs[cur][(db * 16 + l4) * 64 +
                                           (((2 * f + (g >> 1)) ^ (l4 & 7)) * 8 +
                                            (g & 1) * 4)];
        o[0][db] = __builtin_amdgcn_mfma_f32_16x16x16f16(pf[0][f], vf, o[0][db], 0, 0, 0);
        o[1][db] = __builtin_amdgcn_mfma_f32_16x16x16f16(pf[1][f], vf, o[1][db], 0, 0, 0);
      }
    }
    __syncthreads();
  }

  // ---- epilogue: out[b, qw + qs*16 + g*4+jj, hh*64 + db*16 + l4]
#pragma unroll
  for (int qs = 0; qs < 2; ++qs) {
    float invq = 1.f / lsum[qs];
    float inv[4];
#pragma unroll
    for (int jj = 0; jj < 4; ++jj) inv[jj] = __shfl(invq, g * 4 + jj);
#pragma unroll
    for (int db = 0; db < 4; ++db)
#pragma unroll
      for (int jj = 0; jj < 4; ++jj)
        Og[((size_t)b * 2048 + qw + qs * 16 + g * 4 + jj) * 1024 + hh * 64 +
           db * 16 + l4] = f2bf(o[qs][db][jj] * inv[jj]);
  }
#undef STAGE
}

// ---------------------------------------------------------------- launch
extern "C" void kernel_launch(void* const* d_in, const int* in_sizes, int n_in,
                              void* d_out, int out_size, void* d_ws, size_t ws_size,
                              hipStream_t stream) {
  const float* x = (const float*)d_in[0];
  const float* w_qkv = (const float*)d_in[1];
  const float* b_qkv = (const float*)d_in[2];
  const float* w_proj = (const float*)d_in[3];
  const float* b_proj = (const float*)d_in[4];
  float* out = (float*)d_out;

  char* p = (char*)d_ws;
  unsigned short* xb = (unsigned short*)p;     p += (size_t)8192 * 1024 * 2;
  unsigned short* wqkvb = (unsigned short*)p;  p += (size_t)3072 * 1024 * 2;
  unsigned short* wprojb = (unsigned short*)p; p += (size_t)1024 * 1024 * 2;
  unsigned short* qb = (unsigned short*)p;     p += (size_t)64 * 2048 * 64 * 2;
  unsigned short* kb = (unsigned short*)p;     p += (size_t)64 * 2048 * 64 * 2;
  _Float16* vtb = (_Float16*)p;                p += (size_t)64 * 64 * 2048 * 2;
  unsigned short* attnb = (unsigned short*)p;  p += (size_t)8192 * 1024 * 2;

  cvt_f32_bf16<<<dim3(8192), dim3(256), 0, stream>>>(x, xb, 8192 * 1024);
  cvt_f32_bf16<<<dim3(3072), dim3(256), 0, stream>>>(w_qkv, wqkvb, 3072 * 1024);
  cvt_f32_bf16<<<dim3(1024), dim3(256), 0, stream>>>(w_proj, wprojb, 1024 * 1024);

  gemm_bt<1><<<dim3(64 * 24), dim3(256), 0, stream>>>(
      xb, wqkvb, b_qkv, nullptr, qb, kb, vtb, 8192, 3072, 1024);

  attn_fwd<<<dim3(1024), dim3(256), 0, stream>>>(qb, kb, vtb, attnb);

  gemm_bt<0><<<dim3(64 * 8), dim3(256), 0, stream>>>(
      attnb, wprojb, b_proj, out, nullptr, nullptr, nullptr, 8192, 1024, 1024);
}

// Round 7
// 225.914 us; speedup vs baseline: 3.8939x; 1.0133x over previous
//
#include <hip/hip_runtime.h>
#include <stdint.h>

typedef short short8 __attribute__((ext_vector_type(8)));
typedef _Float16 half4 __attribute__((ext_vector_type(4)));
typedef __fp16 fp16x2 __attribute__((ext_vector_type(2)));
typedef unsigned int uint2v __attribute__((ext_vector_type(2)));
typedef float floatx4 __attribute__((ext_vector_type(4)));

#define LOG2E 1.44269504088896340736f
#define QSCALE (0.125f * LOG2E)   // SCALE * log2(e), folded into Q

static __device__ __forceinline__ unsigned short f2bf(float f) {
  unsigned int u = __float_as_uint(f);
  u += 0x7fffu + ((u >> 16) & 1u);
  return (unsigned short)(u >> 16);
}

static __device__ __forceinline__ float fexp2(float x) {
#if __has_builtin(__builtin_amdgcn_exp2f)
  return __builtin_amdgcn_exp2f(x);
#else
  return exp2f(x);
#endif
}

#define GLD_LDS16(gp, lp)                                                      \
  __builtin_amdgcn_global_load_lds(                                            \
      (const __attribute__((address_space(1))) void*)(gp),                     \
      (__attribute__((address_space(3))) void*)(lp), 16, 0, 0)

// ---------------------------------------------------------------- convert
__global__ __launch_bounds__(256) void cvt_f32_bf16(
    const float* __restrict__ in, unsigned short* __restrict__ out, int n) {
  int i = (blockIdx.x * 256 + threadIdx.x) * 4;
  if (i >= n) return;
  float4 v = *(const float4*)(in + i);
  ushort4 u;
  u.x = f2bf(v.x); u.y = f2bf(v.y); u.z = f2bf(v.z); u.w = f2bf(v.w);
  *(ushort4*)(out + i) = u;
}

// ---------------------------------------------------------------- GEMM
// C[M,N] = A[M,K] @ B[N,K]^T + bias   (A,B bf16 row-major, K contiguous)
// MODE 0: write fp32 C to outF.
// MODE 1: qkv epilogue -> q(*QSCALE)[B,h,T,d] bf16, k[B,h,T,d] bf16,
//         vT[B,h,d,T] as f16.
template <int MODE>
__global__ __launch_bounds__(256, 2) void gemm_bt(
    const unsigned short* __restrict__ A, const unsigned short* __restrict__ Bm,
    const float* __restrict__ bias, float* __restrict__ outF,
    unsigned short* __restrict__ qo, unsigned short* __restrict__ ko,
    _Float16* __restrict__ vto, int M, int N, int K) {
  __shared__ unsigned short As[128 * 64];
  __shared__ unsigned short Bs[128 * 64];
  const int tid = threadIdx.x;
  const int w = tid >> 6, l = tid & 63;
  const int lr = l & 15, lg = l >> 4;
  const int nbn = N >> 7;
  const int nwg = gridDim.x;
  const int bid = blockIdx.x;
  const int cpx = nwg >> 3;
  const int swz = (bid & 7) * cpx + (bid >> 3);
  const int bm = swz / nbn, bn = swz % nbn;
  const int wm = w >> 1, wn = w & 1;

  floatx4 acc[4][4];
#pragma unroll
  for (int i = 0; i < 4; ++i)
#pragma unroll
    for (int j = 0; j < 4; ++j) acc[i][j] = (floatx4){0.f, 0.f, 0.f, 0.f};

  for (int k0 = 0; k0 < K; k0 += 64) {
#pragma unroll
    for (int i = 0; i < 4; ++i) {
      int c = i * 256 + tid;
      const unsigned short* ga =
          A + ((size_t)bm * 128 + (c >> 3)) * K + k0 + (c & 7) * 8;
      GLD_LDS16(ga, As + (size_t)(i * 256 + w * 64) * 8);
    }
#pragma unroll
    for (int i = 0; i < 4; ++i) {
      int c = i * 256 + tid;
      const unsigned short* gb =
          Bm + ((size_t)bn * 128 + (c >> 3)) * K + k0 + (c & 7) * 8;
      GLD_LDS16(gb, Bs + (size_t)(i * 256 + w * 64) * 8);
    }
    __syncthreads();
#pragma unroll
    for (int kk = 0; kk < 2; ++kk) {
      short8 af[4], bf[4];
#pragma unroll
      for (int i = 0; i < 4; ++i)
        af[i] = *(const short8*)&As[(wm * 64 + i * 16 + lr) * 64 + kk * 32 + lg * 8];
#pragma unroll
      for (int j = 0; j < 4; ++j)
        bf[j] = *(const short8*)&Bs[(wn * 64 + j * 16 + lr) * 64 + kk * 32 + lg * 8];
#pragma unroll
      for (int i = 0; i < 4; ++i)
#pragma unroll
        for (int j = 0; j < 4; ++j)
          acc[i][j] = __builtin_amdgcn_mfma_f32_16x16x32_bf16(af[i], bf[j],
                                                              acc[i][j], 0, 0, 0);
    }
    __syncthreads();
  }

#pragma unroll
  for (int i = 0; i < 4; ++i) {
    int row0 = bm * 128 + wm * 64 + i * 16 + lg * 4;
#pragma unroll
    for (int j = 0; j < 4; ++j) {
      int col = bn * 128 + wn * 64 + j * 16 + lr;
      float bv = bias[col];
#pragma unroll
      for (int jj = 0; jj < 4; ++jj) {
        float v = acc[i][j][jj] + bv;
        int r = row0 + jj;
        if (MODE == 0) {
          outF[(size_t)r * N + col] = v;
        } else {
          int three = col >> 10, cc = col & 1023;
          int h = cc >> 6, d = cc & 63;
          int b = r >> 11, t = r & 2047;
          if (three == 0)
            qo[(((size_t)(b * 16 + h)) * 2048 + t) * 64 + d] = f2bf(v * QSCALE);
          else if (three == 1)
            ko[(((size_t)(b * 16 + h)) * 2048 + t) * 64 + d] = f2bf(v);
          else
            vto[(((size_t)(b * 16 + h)) * 64 + d) * 2048 + t] = (_Float16)v;
        }
      }
    }
  }
}

// ---------------------------------------------------------------- attention
// Same verified math/layouts as round 5 (16x16 MFMA family, swapped QK,
// LDS-staged K/V with 16B XOR swizzle). Round-6/7 changes (VALU/critical-path):
//  - lsum: per-lane partials (lp), cross-lane reduce ONCE at epilogue.
//  - defer-max test on per-lane partial maxes (all-partials-bounded <=>
//    row-max-bounded); the 2-shfl max reduce runs only inside the rare
//    rescale branch. Common path has ZERO cross-lane ops; exp uses stale m.
//  - P->f16 via packed cvt_pkrtz (returns __fp16x2 -> bit_cast).
__global__ __launch_bounds__(256, 3) void attn_fwd(
    const unsigned short* __restrict__ Qg, const unsigned short* __restrict__ Kg,
    const _Float16* __restrict__ VTg, unsigned short* __restrict__ Og) {
  __shared__ unsigned short Ks[2][64 * 64];
  __shared__ _Float16 Vs[2][64 * 64];

  const int bid0 = blockIdx.x;
  const int bid = (bid0 & 7) * 128 + (bid0 >> 3);  // 8 bh per XCD (K/V=4MB ~ L2)
  const int bh = bid >> 4, qt = bid & 15;
  const int b = bh >> 4, hh = bh & 15;
  const int tid = threadIdx.x, w = tid >> 6, l = tid & 63;
  const int l4 = l & 15, g = l >> 4;
  const unsigned short* Q = Qg + (size_t)bh * (2048 * 64);
  const unsigned short* Kp = Kg + (size_t)bh * (2048 * 64);
  const _Float16* VT = VTg + (size_t)bh * (64 * 2048);
  const int qw = qt * 128 + w * 32;

#define STAGE(bufidx, tt)                                                     \
  do {                                                                        \
    int c0 = tid, c1 = 256 + tid;                                             \
    int r0 = c0 >> 3, s0 = (c0 & 7) ^ (r0 & 7);                               \
    int r1 = c1 >> 3, s1 = (c1 & 7) ^ (r1 & 7);                               \
    GLD_LDS16(Kp + (size_t)((tt) + r0) * 64 + s0 * 8, &Ks[bufidx][c0 * 8]);   \
    GLD_LDS16(Kp + (size_t)((tt) + r1) * 64 + s1 * 8, &Ks[bufidx][c1 * 8]);   \
    GLD_LDS16(VT + (size_t)r0 * 2048 + (tt) + s0 * 8, &Vs[bufidx][c0 * 8]);   \
    GLD_LDS16(VT + (size_t)r1 * 2048 + (tt) + s1 * 8, &Vs[bufidx][c1 * 8]);   \
  } while (0)

  // Q B-frags for two 16-q subtiles (col = l4 = q, k = c*32 + g*8 + j)
  short8 qf[2][2];
#pragma unroll
  for (int qs = 0; qs < 2; ++qs)
#pragma unroll
    for (int c = 0; c < 2; ++c)
      qf[qs][c] =
          *(const short8*)&Q[(size_t)(qw + qs * 16 + l4) * 64 + c * 32 + g * 8];

  floatx4 o[2][4];
#pragma unroll
  for (int qs = 0; qs < 2; ++qs)
#pragma unroll
    for (int db = 0; db < 4; ++db) o[qs][db] = (floatx4){0.f, 0.f, 0.f, 0.f};
  float m[2] = {-__builtin_inff(), -__builtin_inff()};
  float lp[2] = {0.f, 0.f};  // per-lane partial row-sums (reduced at end)

  STAGE(0, 0);
  __syncthreads();

  for (int it = 0; it < 32; ++it) {
    const int cur = it & 1;
    if (it + 1 < 32) STAGE(cur ^ 1, (it + 1) * 64);

    // ---- S^T[qs][f] = K_f @ Q^T ; K frags shared across both q-subtiles
    floatx4 s[2][4];
#pragma unroll
    for (int f = 0; f < 4; ++f) {
      short8 kf0 = *(const short8*)&Ks[cur][(f * 16 + l4) * 64 +
                                            ((g ^ (l4 & 7)) * 8)];
      short8 kf1 = *(const short8*)&Ks[cur][(f * 16 + l4) * 64 +
                                            (((4 + g) ^ (l4 & 7)) * 8)];
      floatx4 z = (floatx4){0.f, 0.f, 0.f, 0.f};
      floatx4 t00 = __builtin_amdgcn_mfma_f32_16x16x32_bf16(kf0, qf[0][0], z, 0, 0, 0);
      s[0][f] = __builtin_amdgcn_mfma_f32_16x16x32_bf16(kf1, qf[0][1], t00, 0, 0, 0);
      floatx4 t10 = __builtin_amdgcn_mfma_f32_16x16x32_bf16(kf0, qf[1][0], z, 0, 0, 0);
      s[1][f] = __builtin_amdgcn_mfma_f32_16x16x32_bf16(kf1, qf[1][1], t10, 0, 0, 0);
    }

    // ---- online softmax per subtile (log2 domain, q = l4 col domain)
    half4 pf[2][4];
#pragma unroll
    for (int qs = 0; qs < 2; ++qs) {
      // per-lane partial max (off the critical path; exp uses stale m)
      float a0 = fmaxf(fmaxf(s[qs][0][0], s[qs][0][1]), fmaxf(s[qs][0][2], s[qs][0][3]));
      float a1 = fmaxf(fmaxf(s[qs][1][0], s[qs][1][1]), fmaxf(s[qs][1][2], s[qs][1][3]));
      float a2 = fmaxf(fmaxf(s[qs][2][0], s[qs][2][1]), fmaxf(s[qs][2][2], s[qs][2][3]));
      float a3 = fmaxf(fmaxf(s[qs][3][0], s[qs][3][1]), fmaxf(s[qs][3][2], s[qs][3][3]));
      float pp = fmaxf(fmaxf(a0, a1), fmaxf(a2, a3));

      // defer-max: all partials bounded <=> true row max bounded (P <= 2^8)
      if (!__all(pp - m[qs] <= 8.0f)) {
        float pmf = fmaxf(pp, __shfl_xor(pp, 16));
        pmf = fmaxf(pmf, __shfl_xor(pmf, 32));
        float mo = m[qs];
        m[qs] = fmaxf(mo, pmf);
        float al = fexp2(mo - m[qs]);
        lp[qs] *= al;
        // o rows are q = g*4+jj (row domain); al lives at q = l4 -> shfl.
#pragma unroll
        for (int jj = 0; jj < 4; ++jj) {
          float alr = __shfl(al, g * 4 + jj);
          o[qs][0][jj] *= alr; o[qs][1][jj] *= alr;
          o[qs][2][jj] *= alr; o[qs][3][jj] *= alr;
        }
      }

      float rs = 0.f;
#pragma unroll
      for (int f = 0; f < 4; ++f) {
        float p0 = fexp2(s[qs][f][0] - m[qs]), p1 = fexp2(s[qs][f][1] - m[qs]);
        float p2 = fexp2(s[qs][f][2] - m[qs]), p3 = fexp2(s[qs][f][3] - m[qs]);
        rs += (p0 + p1) + (p2 + p3);
        fp16x2 plo = __builtin_amdgcn_cvt_pkrtz(p0, p1);
        fp16x2 phi = __builtin_amdgcn_cvt_pkrtz(p2, p3);
        uint2v u;
        u.x = __builtin_bit_cast(unsigned int, plo);
        u.y = __builtin_bit_cast(unsigned int, phi);
        pf[qs][f] = __builtin_bit_cast(half4, u);
      }
      lp[qs] += rs;  // per-lane partial; cross-lane reduce deferred to end
    }

    // ---- O += P @ V ; V frags shared across both q-subtiles
#pragma unroll
    for (int db = 0; db < 4; ++db) {
#pragma unroll
      for (int f = 0; f < 4; ++f) {
        half4 vf = *(const half4*)&Vs[cur][(db * 16 + l4) * 64 +
                                           (((2 * f + (g >> 1)) ^ (l4 & 7)) * 8 +
                                            (g & 1) * 4)];
        o[0][db] = __builtin_amdgcn_mfma_f32_16x16x16f16(pf[0][f], vf, o[0][db], 0, 0, 0);
        o[1][db] = __builtin_amdgcn_mfma_f32_16x16x16f16(pf[1][f], vf, o[1][db], 0, 0, 0);
      }
    }
    __syncthreads();
  }

  // ---- epilogue: reduce lp across the 4 g-lanes, then normalize + store
#pragma unroll
  for (int qs = 0; qs < 2; ++qs) {
    float ls = lp[qs];
    ls += __shfl_xor(ls, 16);
    ls += __shfl_xor(ls, 32);
    float invq = 1.f / ls;
    float inv[4];
#pragma unroll
    for (int jj = 0; jj < 4; ++jj) inv[jj] = __shfl(invq, g * 4 + jj);
#pragma unroll
    for (int db = 0; db < 4; ++db)
#pragma unroll
      for (int jj = 0; jj < 4; ++jj)
        Og[((size_t)b * 2048 + qw + qs * 16 + g * 4 + jj) * 1024 + hh * 64 +
           db * 16 + l4] = f2bf(o[qs][db][jj] * inv[jj]);
  }
#undef STAGE
}

// ---------------------------------------------------------------- launch
extern "C" void kernel_launch(void* const* d_in, const int* in_sizes, int n_in,
                              void* d_out, int out_size, void* d_ws, size_t ws_size,
                              hipStream_t stream) {
  const float* x = (const float*)d_in[0];
  const float* w_qkv = (const float*)d_in[1];
  const float* b_qkv = (const float*)d_in[2];
  const float* w_proj = (const float*)d_in[3];
  const float* b_proj = (const float*)d_in[4];
  float* out = (float*)d_out;

  char* p = (char*)d_ws;
  unsigned short* xb = (unsigned short*)p;     p += (size_t)8192 * 1024 * 2;
  unsigned short* wqkvb = (unsigned short*)p;  p += (size_t)3072 * 1024 * 2;
  unsigned short* wprojb = (unsigned short*)p; p += (size_t)1024 * 1024 * 2;
  unsigned short* qb = (unsigned short*)p;     p += (size_t)64 * 2048 * 64 * 2;
  unsigned short* kb = (unsigned short*)p;     p += (size_t)64 * 2048 * 64 * 2;
  _Float16* vtb = (_Float16*)p;                p += (size_t)64 * 64 * 2048 * 2;
  unsigned short* attnb = (unsigned short*)p;  p += (size_t)8192 * 1024 * 2;

  cvt_f32_bf16<<<dim3(8192), dim3(256), 0, stream>>>(x, xb, 8192 * 1024);
  cvt_f32_bf16<<<dim3(3072), dim3(256), 0, stream>>>(w_qkv, wqkvb, 3072 * 1024);
  cvt_f32_bf16<<<dim3(1024), dim3(256), 0, stream>>>(w_proj, wprojb, 1024 * 1024);

  gemm_bt<1><<<dim3(64 * 24), dim3(256), 0, stream>>>(
      xb, wqkvb, b_qkv, nullptr, qb, kb, vtb, 8192, 3072, 1024);

  attn_fwd<<<dim3(1024), dim3(256), 0, stream>>>(qb, kb, vtb, attnb);

  gemm_bt<0><<<dim3(64 * 8), dim3(256), 0, stream>>>(
      attnb, wprojb, b_proj, out, nullptr, nullptr, nullptr, 8192, 1024, 1024);
}

// Round 8
// 217.841 us; speedup vs baseline: 4.0382x; 1.0371x over previous
//
#include <hip/hip_runtime.h>
#include <stdint.h>

typedef short short8 __attribute__((ext_vector_type(8)));
typedef _Float16 half4 __attribute__((ext_vector_type(4)));
typedef __fp16 fp16x2 __attribute__((ext_vector_type(2)));
typedef unsigned int uint2v __attribute__((ext_vector_type(2)));
typedef float floatx4 __attribute__((ext_vector_type(4)));

#define LOG2E 1.44269504088896340736f
#define QSCALE (0.125f * LOG2E)   // SCALE * log2(e), folded into Q

static __device__ __forceinline__ unsigned short f2bf(float f) {
  unsigned int u = __float_as_uint(f);
  u += 0x7fffu + ((u >> 16) & 1u);
  return (unsigned short)(u >> 16);
}

static __device__ __forceinline__ float fexp2(float x) {
#if __has_builtin(__builtin_amdgcn_exp2f)
  return __builtin_amdgcn_exp2f(x);
#else
  return exp2f(x);
#endif
}

#define GLD_LDS16(gp, lp)                                                      \
  __builtin_amdgcn_global_load_lds(                                            \
      (const __attribute__((address_space(1))) void*)(gp),                     \
      (__attribute__((address_space(3))) void*)(lp), 16, 0, 0)

// ---------------------------------------------------------------- convert
__global__ __launch_bounds__(256) void cvt_f32_bf16(
    const float* __restrict__ in, unsigned short* __restrict__ out, int n) {
  int i = (blockIdx.x * 256 + threadIdx.x) * 4;
  if (i >= n) return;
  float4 v = *(const float4*)(in + i);
  ushort4 u;
  u.x = f2bf(v.x); u.y = f2bf(v.y); u.z = f2bf(v.z); u.w = f2bf(v.w);
  *(ushort4*)(out + i) = u;
}

// ---------------------------------------------------------------- GEMM
// C[M,N] = A[M,K] @ B[N,K]^T + bias   (A,B bf16 row-major, K contiguous)
// MODE 0: write fp32 C to outF.
// MODE 1: qkv epilogue -> q(*QSCALE)[B,h,T,d] bf16, k[B,h,T,d] bf16,
//         vT[B,h,d,T] as f16.
template <int MODE>
__global__ __launch_bounds__(256, 2) void gemm_bt(
    const unsigned short* __restrict__ A, const unsigned short* __restrict__ Bm,
    const float* __restrict__ bias, float* __restrict__ outF,
    unsigned short* __restrict__ qo, unsigned short* __restrict__ ko,
    _Float16* __restrict__ vto, int M, int N, int K) {
  __shared__ unsigned short As[128 * 64];
  __shared__ unsigned short Bs[128 * 64];
  const int tid = threadIdx.x;
  const int w = tid >> 6, l = tid & 63;
  const int lr = l & 15, lg = l >> 4;
  const int nbn = N >> 7;
  const int nwg = gridDim.x;
  const int bid = blockIdx.x;
  const int cpx = nwg >> 3;
  const int swz = (bid & 7) * cpx + (bid >> 3);
  const int bm = swz / nbn, bn = swz % nbn;
  const int wm = w >> 1, wn = w & 1;

  floatx4 acc[4][4];
#pragma unroll
  for (int i = 0; i < 4; ++i)
#pragma unroll
    for (int j = 0; j < 4; ++j) acc[i][j] = (floatx4){0.f, 0.f, 0.f, 0.f};

  for (int k0 = 0; k0 < K; k0 += 64) {
#pragma unroll
    for (int i = 0; i < 4; ++i) {
      int c = i * 256 + tid;
      const unsigned short* ga =
          A + ((size_t)bm * 128 + (c >> 3)) * K + k0 + (c & 7) * 8;
      GLD_LDS16(ga, As + (size_t)(i * 256 + w * 64) * 8);
    }
#pragma unroll
    for (int i = 0; i < 4; ++i) {
      int c = i * 256 + tid;
      const unsigned short* gb =
          Bm + ((size_t)bn * 128 + (c >> 3)) * K + k0 + (c & 7) * 8;
      GLD_LDS16(gb, Bs + (size_t)(i * 256 + w * 64) * 8);
    }
    __syncthreads();
#pragma unroll
    for (int kk = 0; kk < 2; ++kk) {
      short8 af[4], bf[4];
#pragma unroll
      for (int i = 0; i < 4; ++i)
        af[i] = *(const short8*)&As[(wm * 64 + i * 16 + lr) * 64 + kk * 32 + lg * 8];
#pragma unroll
      for (int j = 0; j < 4; ++j)
        bf[j] = *(const short8*)&Bs[(wn * 64 + j * 16 + lr) * 64 + kk * 32 + lg * 8];
#pragma unroll
      for (int i = 0; i < 4; ++i)
#pragma unroll
        for (int j = 0; j < 4; ++j)
          acc[i][j] = __builtin_amdgcn_mfma_f32_16x16x32_bf16(af[i], bf[j],
                                                              acc[i][j], 0, 0, 0);
    }
    __syncthreads();
  }

#pragma unroll
  for (int i = 0; i < 4; ++i) {
    int row0 = bm * 128 + wm * 64 + i * 16 + lg * 4;
#pragma unroll
    for (int j = 0; j < 4; ++j) {
      int col = bn * 128 + wn * 64 + j * 16 + lr;
      float bv = bias[col];
#pragma unroll
      for (int jj = 0; jj < 4; ++jj) {
        float v = acc[i][j][jj] + bv;
        int r = row0 + jj;
        if (MODE == 0) {
          outF[(size_t)r * N + col] = v;
        } else {
          int three = col >> 10, cc = col & 1023;
          int h = cc >> 6, d = cc & 63;
          int b = r >> 11, t = r & 2047;
          if (three == 0)
            qo[(((size_t)(b * 16 + h)) * 2048 + t) * 64 + d] = f2bf(v * QSCALE);
          else if (three == 1)
            ko[(((size_t)(b * 16 + h)) * 2048 + t) * 64 + d] = f2bf(v);
          else
            vto[(((size_t)(b * 16 + h)) * 64 + d) * 2048 + t] = (_Float16)v;
        }
      }
    }
  }
}

// ---------------------------------------------------------------- attention
// Verified math/layouts from rounds 4-7 (16x16 MFMA family, swapped QK,
// LDS-staged K/V, 16B XOR swizzle both-sides). Round-8 changes (issue-bound):
//  - all LDS read addresses flattened to lane-base + compile-time immediate
//    (swizzled slot for kf0/kf1 is f-invariant; V gets 4 bases);
//    #pragma unroll 2 makes `cur` static so buffer offset folds into imm.
//  - defer-max test moved to per-lane partial sum rs (rs<=256 => all P<=2^8);
//    slow path (rare; always at it=0) recomputes max + re-exponentiates.
__global__ __launch_bounds__(256, 3) void attn_fwd(
    const unsigned short* __restrict__ Qg, const unsigned short* __restrict__ Kg,
    const _Float16* __restrict__ VTg, unsigned short* __restrict__ Og) {
  __shared__ unsigned short Ks[2][64 * 64];
  __shared__ _Float16 Vs[2][64 * 64];

  const int bid0 = blockIdx.x;
  const int bid = (bid0 & 7) * 128 + (bid0 >> 3);  // 8 bh per XCD (K/V=4MB ~ L2)
  const int bh = bid >> 4, qt = bid & 15;
  const int b = bh >> 4, hh = bh & 15;
  const int tid = threadIdx.x, w = tid >> 6, l = tid & 63;
  const int l4 = l & 15, g = l >> 4;
  const unsigned short* Q = Qg + (size_t)bh * (2048 * 64);
  const unsigned short* Kp = Kg + (size_t)bh * (2048 * 64);
  const _Float16* VT = VTg + (size_t)bh * (64 * 2048);
  const int qw = qt * 128 + w * 32;

  // staging pointers (chunk c: row=c>>3, slot=c&7; source slot XOR row&7)
  const int c0 = tid, c1 = 256 + tid;
  const int r0 = c0 >> 3, s0 = (c0 & 7) ^ (r0 & 7);
  const int r1 = c1 >> 3, s1 = (c1 & 7) ^ (r1 & 7);
  const unsigned short* kp0 = Kp + (size_t)r0 * 64 + s0 * 8;
  const unsigned short* kp1 = Kp + (size_t)r1 * 64 + s1 * 8;
  const _Float16* vp0 = VT + (size_t)r0 * 2048 + s0 * 8;
  const _Float16* vp1 = VT + (size_t)r1 * 2048 + s1 * 8;
  unsigned short* ksd0 = &Ks[0][c0 * 8];
  unsigned short* ksd1 = &Ks[0][c1 * 8];
  _Float16* vsd0 = &Vs[0][c0 * 8];
  _Float16* vsd1 = &Vs[0][c1 * 8];

#define STAGE(bufofs, tt)                                                     \
  do {                                                                        \
    GLD_LDS16(kp0 + (size_t)(tt) * 64, ksd0 + (bufofs) * 4096);               \
    GLD_LDS16(kp1 + (size_t)(tt) * 64, ksd1 + (bufofs) * 4096);               \
    GLD_LDS16(vp0 + (tt), vsd0 + (bufofs) * 4096);                            \
    GLD_LDS16(vp1 + (tt), vsd1 + (bufofs) * 4096);                            \
  } while (0)

  // LDS read bases (ushort/f16 element units); f/db offsets are immediates
  const int kb0 = l4 * 64 + ((g ^ (l4 & 7)) * 8);
  const int kb1 = l4 * 64 + (((4 + g) ^ (l4 & 7)) * 8);
  int vb[4];
#pragma unroll
  for (int f = 0; f < 4; ++f)
    vb[f] = l4 * 64 + (((2 * f + (g >> 1)) ^ (l4 & 7)) * 8 + (g & 1) * 4);

  // Q B-frags for two 16-q subtiles (col = l4 = q, k = c*32 + g*8 + j)
  short8 qf[2][2];
#pragma unroll
  for (int qs = 0; qs < 2; ++qs)
#pragma unroll
    for (int c = 0; c < 2; ++c)
      qf[qs][c] =
          *(const short8*)&Q[(size_t)(qw + qs * 16 + l4) * 64 + c * 32 + g * 8];

  floatx4 o[2][4];
#pragma unroll
  for (int qs = 0; qs < 2; ++qs)
#pragma unroll
    for (int db = 0; db < 4; ++db) o[qs][db] = (floatx4){0.f, 0.f, 0.f, 0.f};
  float m[2] = {-__builtin_inff(), -__builtin_inff()};
  float lp[2] = {0.f, 0.f};  // per-lane partial row-sums (reduced at end)

  STAGE(0, 0);
  __syncthreads();

#pragma unroll 2
  for (int it = 0; it < 32; ++it) {
    const int cur = it & 1;
    if (it + 1 < 32) STAGE(cur ^ 1, (it + 1) * 64);

    // ---- S^T[qs][f] = K_f @ Q^T ; K frags shared across both q-subtiles
    floatx4 s[2][4];
#pragma unroll
    for (int f = 0; f < 4; ++f) {
      short8 kf0 = *(const short8*)&Ks[cur][kb0 + f * 1024];
      short8 kf1 = *(const short8*)&Ks[cur][kb1 + f * 1024];
      floatx4 z = (floatx4){0.f, 0.f, 0.f, 0.f};
      floatx4 t00 = __builtin_amdgcn_mfma_f32_16x16x32_bf16(kf0, qf[0][0], z, 0, 0, 0);
      s[0][f] = __builtin_amdgcn_mfma_f32_16x16x32_bf16(kf1, qf[0][1], t00, 0, 0, 0);
      floatx4 t10 = __builtin_amdgcn_mfma_f32_16x16x32_bf16(kf0, qf[1][0], z, 0, 0, 0);
      s[1][f] = __builtin_amdgcn_mfma_f32_16x16x32_bf16(kf1, qf[1][1], t10, 0, 0, 0);
    }

    // ---- online softmax per subtile (log2 domain, q = l4 col domain)
    half4 pf[2][4];
#pragma unroll
    for (int qs = 0; qs < 2; ++qs) {
      float e[16];
      float rs = 0.f;
#pragma unroll
      for (int f = 0; f < 4; ++f)
#pragma unroll
        for (int jj = 0; jj < 4; ++jj) {
          float pv = fexp2(s[qs][f][jj] - m[qs]);
          e[f * 4 + jj] = pv;
          rs += pv;
        }

      // defer-max: rs >= every positive term, so rs<=256 => all P <= 2^8.
      // Slow path (always at it=0 where m=-inf => rs=inf): recompute.
      if (!__all(rs <= 256.0f)) {
        float a0 = fmaxf(fmaxf(s[qs][0][0], s[qs][0][1]), fmaxf(s[qs][0][2], s[qs][0][3]));
        float a1 = fmaxf(fmaxf(s[qs][1][0], s[qs][1][1]), fmaxf(s[qs][1][2], s[qs][1][3]));
        float a2 = fmaxf(fmaxf(s[qs][2][0], s[qs][2][1]), fmaxf(s[qs][2][2], s[qs][2][3]));
        float a3 = fmaxf(fmaxf(s[qs][3][0], s[qs][3][1]), fmaxf(s[qs][3][2], s[qs][3][3]));
        float pp = fmaxf(fmaxf(a0, a1), fmaxf(a2, a3));
        pp = fmaxf(pp, __shfl_xor(pp, 16));
        pp = fmaxf(pp, __shfl_xor(pp, 32));
        float mo = m[qs];
        m[qs] = fmaxf(mo, pp);
        float al = fexp2(mo - m[qs]);   // 0 when mo = -inf
        lp[qs] *= al;
        // o rows are q = g*4+jj (row domain); al lives at q = l4 -> shfl.
#pragma unroll
        for (int jj = 0; jj < 4; ++jj) {
          float alr = __shfl(al, g * 4 + jj);
          o[qs][0][jj] *= alr; o[qs][1][jj] *= alr;
          o[qs][2][jj] *= alr; o[qs][3][jj] *= alr;
        }
        rs = 0.f;
#pragma unroll
        for (int f = 0; f < 4; ++f)
#pragma unroll
          for (int jj = 0; jj < 4; ++jj) {
            float pv = fexp2(s[qs][f][jj] - m[qs]);
            e[f * 4 + jj] = pv;
            rs += pv;
          }
      }
      lp[qs] += rs;

#pragma unroll
      for (int f = 0; f < 4; ++f) {
        fp16x2 plo = __builtin_amdgcn_cvt_pkrtz(e[f * 4 + 0], e[f * 4 + 1]);
        fp16x2 phi = __builtin_amdgcn_cvt_pkrtz(e[f * 4 + 2], e[f * 4 + 3]);
        uint2v u;
        u.x = __builtin_bit_cast(unsigned int, plo);
        u.y = __builtin_bit_cast(unsigned int, phi);
        pf[qs][f] = __builtin_bit_cast(half4, u);
      }
    }

    // ---- O += P @ V ; V frags shared across both q-subtiles
#pragma unroll
    for (int db = 0; db < 4; ++db) {
#pragma unroll
      for (int f = 0; f < 4; ++f) {
        half4 vf = *(const half4*)&Vs[cur][vb[f] + db * 1024];
        o[0][db] = __builtin_amdgcn_mfma_f32_16x16x16f16(pf[0][f], vf, o[0][db], 0, 0, 0);
        o[1][db] = __builtin_amdgcn_mfma_f32_16x16x16f16(pf[1][f], vf, o[1][db], 0, 0, 0);
      }
    }
    __syncthreads();
  }

  // ---- epilogue: reduce lp across the 4 g-lanes, then normalize + store
#pragma unroll
  for (int qs = 0; qs < 2; ++qs) {
    float ls = lp[qs];
    ls += __shfl_xor(ls, 16);
    ls += __shfl_xor(ls, 32);
    float invq = 1.f / ls;
    float inv[4];
#pragma unroll
    for (int jj = 0; jj < 4; ++jj) inv[jj] = __shfl(invq, g * 4 + jj);
#pragma unroll
    for (int db = 0; db < 4; ++db)
#pragma unroll
      for (int jj = 0; jj < 4; ++jj)
        Og[((size_t)b * 2048 + qw + qs * 16 + g * 4 + jj) * 1024 + hh * 64 +
           db * 16 + l4] = f2bf(o[qs][db][jj] * inv[jj]);
  }
#undef STAGE
}

// ---------------------------------------------------------------- launch
extern "C" void kernel_launch(void* const* d_in, const int* in_sizes, int n_in,
                              void* d_out, int out_size, void* d_ws, size_t ws_size,
                              hipStream_t stream) {
  const float* x = (const float*)d_in[0];
  const float* w_qkv = (const float*)d_in[1];
  const float* b_qkv = (const float*)d_in[2];
  const float* w_proj = (const float*)d_in[3];
  const float* b_proj = (const float*)d_in[4];
  float* out = (float*)d_out;

  char* p = (char*)d_ws;
  unsigned short* xb = (unsigned short*)p;     p += (size_t)8192 * 1024 * 2;
  unsigned short* wqkvb = (unsigned short*)p;  p += (size_t)3072 * 1024 * 2;
  unsigned short* wprojb = (unsigned short*)p; p += (size_t)1024 * 1024 * 2;
  unsigned short* qb = (unsigned short*)p;     p += (size_t)64 * 2048 * 64 * 2;
  unsigned short* kb = (unsigned short*)p;     p += (size_t)64 * 2048 * 64 * 2;
  _Float16* vtb = (_Float16*)p;                p += (size_t)64 * 64 * 2048 * 2;
  unsigned short* attnb = (unsigned short*)p;  p += (size_t)8192 * 1024 * 2;

  cvt_f32_bf16<<<dim3(8192), dim3(256), 0, stream>>>(x, xb, 8192 * 1024);
  cvt_f32_bf16<<<dim3(3072), dim3(256), 0, stream>>>(w_qkv, wqkvb, 3072 * 1024);
  cvt_f32_bf16<<<dim3(1024), dim3(256), 0, stream>>>(w_proj, wprojb, 1024 * 1024);

  gemm_bt<1><<<dim3(64 * 24), dim3(256), 0, stream>>>(
      xb, wqkvb, b_qkv, nullptr, qb, kb, vtb, 8192, 3072, 1024);

  attn_fwd<<<dim3(1024), dim3(256), 0, stream>>>(qb, kb, vtb, attnb);

  gemm_bt<0><<<dim3(64 * 8), dim3(256), 0, stream>>>(
      attnb, wprojb, b_proj, out, nullptr, nullptr, nullptr, 8192, 1024, 1024);
}

// Round 9
// 205.144 us; speedup vs baseline: 4.2882x; 1.0619x over previous
//
#include <hip/hip_runtime.h>
#include <stdint.h>

typedef short short8 __attribute__((ext_vector_type(8)));
typedef _Float16 half4 __attribute__((ext_vector_type(4)));
typedef _Float16 half8 __attribute__((ext_vector_type(8)));
typedef __fp16 fp16x2 __attribute__((ext_vector_type(2)));
typedef unsigned int uint2v __attribute__((ext_vector_type(2)));
typedef unsigned int uintx4 __attribute__((ext_vector_type(4)));
typedef float floatx4 __attribute__((ext_vector_type(4)));

#define LOG2E 1.44269504088896340736f
#define QSCALE (0.125f * LOG2E)   // SCALE * log2(e), folded into Q

static __device__ __forceinline__ unsigned short f2bf(float f) {
  unsigned int u = __float_as_uint(f);
  u += 0x7fffu + ((u >> 16) & 1u);
  return (unsigned short)(u >> 16);
}

static __device__ __forceinline__ float fexp2(float x) {
#if __has_builtin(__builtin_amdgcn_exp2f)
  return __builtin_amdgcn_exp2f(x);
#else
  return exp2f(x);
#endif
}

#define GLD_LDS16(gp, lp)                                                      \
  __builtin_amdgcn_global_load_lds(                                            \
      (const __attribute__((address_space(1))) void*)(gp),                     \
      (__attribute__((address_space(3))) void*)(lp), 16, 0, 0)

// ---------------------------------------------------------------- convert
__global__ __launch_bounds__(256) void cvt_f32_bf16(
    const float* __restrict__ in, unsigned short* __restrict__ out, int n) {
  int i = (blockIdx.x * 256 + threadIdx.x) * 4;
  if (i >= n) return;
  float4 v = *(const float4*)(in + i);
  ushort4 u;
  u.x = f2bf(v.x); u.y = f2bf(v.y); u.z = f2bf(v.z); u.w = f2bf(v.w);
  *(ushort4*)(out + i) = u;
}

// ---------------------------------------------------------------- GEMM
// C[M,N] = A[M,K] @ B[N,K]^T + bias   (A,B bf16 row-major, K contiguous)
// MODE 0: write fp32 C to outF.
// MODE 1: qkv epilogue -> q(*QSCALE)[B,h,T,d] bf16, k[B,h,T,d] bf16,
//         vT[B,h,d,T] as f16.
template <int MODE>
__global__ __launch_bounds__(256, 2) void gemm_bt(
    const unsigned short* __restrict__ A, const unsigned short* __restrict__ Bm,
    const float* __restrict__ bias, float* __restrict__ outF,
    unsigned short* __restrict__ qo, unsigned short* __restrict__ ko,
    _Float16* __restrict__ vto, int M, int N, int K) {
  __shared__ unsigned short As[128 * 64];
  __shared__ unsigned short Bs[128 * 64];
  const int tid = threadIdx.x;
  const int w = tid >> 6, l = tid & 63;
  const int lr = l & 15, lg = l >> 4;
  const int nbn = N >> 7;
  const int nwg = gridDim.x;
  const int bid = blockIdx.x;
  const int cpx = nwg >> 3;
  const int swz = (bid & 7) * cpx + (bid >> 3);
  const int bm = swz / nbn, bn = swz % nbn;
  const int wm = w >> 1, wn = w & 1;

  floatx4 acc[4][4];
#pragma unroll
  for (int i = 0; i < 4; ++i)
#pragma unroll
    for (int j = 0; j < 4; ++j) acc[i][j] = (floatx4){0.f, 0.f, 0.f, 0.f};

  for (int k0 = 0; k0 < K; k0 += 64) {
#pragma unroll
    for (int i = 0; i < 4; ++i) {
      int c = i * 256 + tid;
      const unsigned short* ga =
          A + ((size_t)bm * 128 + (c >> 3)) * K + k0 + (c & 7) * 8;
      GLD_LDS16(ga, As + (size_t)(i * 256 + w * 64) * 8);
    }
#pragma unroll
    for (int i = 0; i < 4; ++i) {
      int c = i * 256 + tid;
      const unsigned short* gb =
          Bm + ((size_t)bn * 128 + (c >> 3)) * K + k0 + (c & 7) * 8;
      GLD_LDS16(gb, Bs + (size_t)(i * 256 + w * 64) * 8);
    }
    __syncthreads();
#pragma unroll
    for (int kk = 0; kk < 2; ++kk) {
      short8 af[4], bf[4];
#pragma unroll
      for (int i = 0; i < 4; ++i)
        af[i] = *(const short8*)&As[(wm * 64 + i * 16 + lr) * 64 + kk * 32 + lg * 8];
#pragma unroll
      for (int j = 0; j < 4; ++j)
        bf[j] = *(const short8*)&Bs[(wn * 64 + j * 16 + lr) * 64 + kk * 32 + lg * 8];
#pragma unroll
      for (int i = 0; i < 4; ++i)
#pragma unroll
        for (int j = 0; j < 4; ++j)
          acc[i][j] = __builtin_amdgcn_mfma_f32_16x16x32_bf16(af[i], bf[j],
                                                              acc[i][j], 0, 0, 0);
    }
    __syncthreads();
  }

#pragma unroll
  for (int i = 0; i < 4; ++i) {
    int row0 = bm * 128 + wm * 64 + i * 16 + lg * 4;
#pragma unroll
    for (int j = 0; j < 4; ++j) {
      int col = bn * 128 + wn * 64 + j * 16 + lr;
      float bv = bias[col];
#pragma unroll
      for (int jj = 0; jj < 4; ++jj) {
        float v = acc[i][j][jj] + bv;
        int r = row0 + jj;
        if (MODE == 0) {
          outF[(size_t)r * N + col] = v;
        } else {
          int three = col >> 10, cc = col & 1023;
          int h = cc >> 6, d = cc & 63;
          int b = r >> 11, t = r & 2047;
          if (three == 0)
            qo[(((size_t)(b * 16 + h)) * 2048 + t) * 64 + d] = f2bf(v * QSCALE);
          else if (three == 1)
            ko[(((size_t)(b * 16 + h)) * 2048 + t) * 64 + d] = f2bf(v);
          else
            vto[(((size_t)(b * 16 + h)) * 64 + d) * 2048 + t] = (_Float16)v;
        }
      }
    }
  }
}

// ---------------------------------------------------------------- attention
// Verified 16x16-family layouts (rounds 4-8). Round-9: PV upgraded to
// mfma_f32_16x16x32_f16 via a kv-permutation of the K tile:
//   K rows staged into LDS at position p from global kv = pi(p), where
//   pi (per 32-block) = p<16 ? (p>>2)*8+(p&3) : ((p-16)>>2)*8+4+(p&3).
//   Then lane (l4,g)'s S^T regs over f-pair {2B,2B+1} hold scores for
//   kv = B*32 + g*8 + {0..7} IN ORDER -> PV A-frag (k=g*8+j) is just the
//   concat of the two cvt_pkrtz pairs; V stays in natural kv order and its
//   B-frag (k=g*8+j) is a contiguous 16B read. PV: 16 MFMA @K=32 (was 32
//   @K=16), V ds_reads 8x16B (was 16x8B). Sum over kv is permutation-
//   invariant since P and V use consistent kv indexing.
__global__ __launch_bounds__(256, 3) void attn_fwd(
    const unsigned short* __restrict__ Qg, const unsigned short* __restrict__ Kg,
    const _Float16* __restrict__ VTg, unsigned short* __restrict__ Og) {
  __shared__ unsigned short Ks[2][64 * 64];
  __shared__ _Float16 Vs[2][64 * 64];

  const int bid0 = blockIdx.x;
  const int bid = (bid0 & 7) * 128 + (bid0 >> 3);  // 8 bh per XCD (K/V=4MB ~ L2)
  const int bh = bid >> 4, qt = bid & 15;
  const int b = bh >> 4, hh = bh & 15;
  const int tid = threadIdx.x, w = tid >> 6, l = tid & 63;
  const int l4 = l & 15, g = l >> 4;
  const unsigned short* Q = Qg + (size_t)bh * (2048 * 64);
  const unsigned short* Kp = Kg + (size_t)bh * (2048 * 64);
  const _Float16* VT = VTg + (size_t)bh * (64 * 2048);
  const int qw = qt * 128 + w * 32;

  // staging: chunk c: position row=c>>3, slot=c&7; source slot XOR (row&7).
  // K source row permuted by pi (position p -> kv), V in natural order.
  const int r0 = tid >> 3;                    // 0..31 (r1 = r0+32, s1 == s0)
  const int s0 = (tid & 7) ^ (r0 & 7);
  const int kv0 = (r0 & 16) ? (((r0 & 15) >> 2) * 8 + 4 + (r0 & 3))
                            : ((r0 >> 2) * 8 + (r0 & 3));
  const unsigned short* kp0 = Kp + (size_t)kv0 * 64 + s0 * 8;
  const unsigned short* kp1 = Kp + (size_t)(kv0 + 32) * 64 + s0 * 8;
  const _Float16* vp0 = VT + (size_t)r0 * 2048 + s0 * 8;
  const _Float16* vp1 = VT + (size_t)(r0 + 32) * 2048 + s0 * 8;
  unsigned short* ksd0 = &Ks[0][tid * 8];
  unsigned short* ksd1 = &Ks[0][(256 + tid) * 8];
  _Float16* vsd0 = &Vs[0][tid * 8];
  _Float16* vsd1 = &Vs[0][(256 + tid) * 8];

#define STAGE(bufofs, tt)                                                     \
  do {                                                                        \
    GLD_LDS16(kp0 + (size_t)(tt) * 64, ksd0 + (bufofs) * 4096);               \
    GLD_LDS16(kp1 + (size_t)(tt) * 64, ksd1 + (bufofs) * 4096);               \
    GLD_LDS16(vp0 + (tt), vsd0 + (bufofs) * 4096);                            \
    GLD_LDS16(vp1 + (tt), vsd1 + (bufofs) * 4096);                            \
  } while (0)

  // LDS read bases (element units); f/db offsets are compile-time imms
  const int kb0 = l4 * 64 + ((g ^ (l4 & 7)) * 8);
  const int kb1 = l4 * 64 + (((4 + g) ^ (l4 & 7)) * 8);
  int vb[2];
#pragma unroll
  for (int B = 0; B < 2; ++B)
    vb[B] = l4 * 64 + (((B * 4 + g) ^ (l4 & 7)) * 8);

  // Q B-frags for two 16-q subtiles (col = l4 = q, k = c*32 + g*8 + j)
  short8 qf[2][2];
#pragma unroll
  for (int qs = 0; qs < 2; ++qs)
#pragma unroll
    for (int c = 0; c < 2; ++c)
      qf[qs][c] =
          *(const short8*)&Q[(size_t)(qw + qs * 16 + l4) * 64 + c * 32 + g * 8];

  floatx4 o[2][4];
#pragma unroll
  for (int qs = 0; qs < 2; ++qs)
#pragma unroll
    for (int db = 0; db < 4; ++db) o[qs][db] = (floatx4){0.f, 0.f, 0.f, 0.f};
  float m[2] = {-__builtin_inff(), -__builtin_inff()};
  float lp[2] = {0.f, 0.f};  // per-lane partial row-sums (reduced at end)

  STAGE(0, 0);
  __syncthreads();

#pragma unroll 2
  for (int it = 0; it < 32; ++it) {
    const int cur = it & 1;
    if (it + 1 < 32) STAGE(cur ^ 1, (it + 1) * 64);

    // ---- S^T[qs][f] = K_f @ Q^T ; K frags shared across both q-subtiles
    floatx4 s[2][4];
#pragma unroll
    for (int f = 0; f < 4; ++f) {
      short8 kf0 = *(const short8*)&Ks[cur][kb0 + f * 1024];
      short8 kf1 = *(const short8*)&Ks[cur][kb1 + f * 1024];
      floatx4 z = (floatx4){0.f, 0.f, 0.f, 0.f};
      floatx4 t00 = __builtin_amdgcn_mfma_f32_16x16x32_bf16(kf0, qf[0][0], z, 0, 0, 0);
      s[0][f] = __builtin_amdgcn_mfma_f32_16x16x32_bf16(kf1, qf[0][1], t00, 0, 0, 0);
      floatx4 t10 = __builtin_amdgcn_mfma_f32_16x16x32_bf16(kf0, qf[1][0], z, 0, 0, 0);
      s[1][f] = __builtin_amdgcn_mfma_f32_16x16x32_bf16(kf1, qf[1][1], t10, 0, 0, 0);
    }

    // ---- online softmax per subtile (log2 domain, q = l4 col domain)
    uint2v pu[2][4];  // packed f16 P, per (qs, f): kv = B*32+g*8+(f&1)*4+jj
#pragma unroll
    for (int qs = 0; qs < 2; ++qs) {
      float e[16];
      float rs = 0.f;
#pragma unroll
      for (int f = 0; f < 4; ++f)
#pragma unroll
        for (int jj = 0; jj < 4; ++jj) {
          float pv = fexp2(s[qs][f][jj] - m[qs]);
          e[f * 4 + jj] = pv;
          rs += pv;
        }

      // defer-max: rs >= every positive term, so rs<=256 => all P <= 2^8.
      // Slow path (always at it=0 where m=-inf => rs=inf): recompute.
      if (!__all(rs <= 256.0f)) {
        float a0 = fmaxf(fmaxf(s[qs][0][0], s[qs][0][1]), fmaxf(s[qs][0][2], s[qs][0][3]));
        float a1 = fmaxf(fmaxf(s[qs][1][0], s[qs][1][1]), fmaxf(s[qs][1][2], s[qs][1][3]));
        float a2 = fmaxf(fmaxf(s[qs][2][0], s[qs][2][1]), fmaxf(s[qs][2][2], s[qs][2][3]));
        float a3 = fmaxf(fmaxf(s[qs][3][0], s[qs][3][1]), fmaxf(s[qs][3][2], s[qs][3][3]));
        float pp = fmaxf(fmaxf(a0, a1), fmaxf(a2, a3));
        pp = fmaxf(pp, __shfl_xor(pp, 16));
        pp = fmaxf(pp, __shfl_xor(pp, 32));
        float mo = m[qs];
        m[qs] = fmaxf(mo, pp);
        float al = fexp2(mo - m[qs]);   // 0 when mo = -inf
        lp[qs] *= al;
        // o rows are q = g*4+jj (row domain); al lives at q = l4 -> shfl.
#pragma unroll
        for (int jj = 0; jj < 4; ++jj) {
          float alr = __shfl(al, g * 4 + jj);
          o[qs][0][jj] *= alr; o[qs][1][jj] *= alr;
          o[qs][2][jj] *= alr; o[qs][3][jj] *= alr;
        }
        rs = 0.f;
#pragma unroll
        for (int f = 0; f < 4; ++f)
#pragma unroll
          for (int jj = 0; jj < 4; ++jj) {
            float pv = fexp2(s[qs][f][jj] - m[qs]);
            e[f * 4 + jj] = pv;
            rs += pv;
          }
      }
      lp[qs] += rs;

#pragma unroll
      for (int f = 0; f < 4; ++f) {
        fp16x2 plo = __builtin_amdgcn_cvt_pkrtz(e[f * 4 + 0], e[f * 4 + 1]);
        fp16x2 phi = __builtin_amdgcn_cvt_pkrtz(e[f * 4 + 2], e[f * 4 + 3]);
        pu[qs][f].x = __builtin_bit_cast(unsigned int, plo);
        pu[qs][f].y = __builtin_bit_cast(unsigned int, phi);
      }
    }

    // ---- O += P @ V  (16x16x32 f16; A = concat of f-pair, B = 16B V read)
#pragma unroll
    for (int B = 0; B < 2; ++B) {
      uintx4 ua0, ua1;
      ua0.x = pu[0][2 * B].x;     ua0.y = pu[0][2 * B].y;
      ua0.z = pu[0][2 * B + 1].x; ua0.w = pu[0][2 * B + 1].y;
      ua1.x = pu[1][2 * B].x;     ua1.y = pu[1][2 * B].y;
      ua1.z = pu[1][2 * B + 1].x; ua1.w = pu[1][2 * B + 1].y;
      half8 pa0 = __builtin_bit_cast(half8, ua0);
      half8 pa1 = __builtin_bit_cast(half8, ua1);
#pragma unroll
      for (int db = 0; db < 4; ++db) {
        half8 vf = *(const half8*)&Vs[cur][vb[B] + db * 1024];
        o[0][db] = __builtin_amdgcn_mfma_f32_16x16x32_f16(pa0, vf, o[0][db], 0, 0, 0);
        o[1][db] = __builtin_amdgcn_mfma_f32_16x16x32_f16(pa1, vf, o[1][db], 0, 0, 0);
      }
    }
    __syncthreads();
  }

  // ---- epilogue: reduce lp across the 4 g-lanes, then normalize + store
#pragma unroll
  for (int qs = 0; qs < 2; ++qs) {
    float ls = lp[qs];
    ls += __shfl_xor(ls, 16);
    ls += __shfl_xor(ls, 32);
    float invq = 1.f / ls;
    float inv[4];
#pragma unroll
    for (int jj = 0; jj < 4; ++jj) inv[jj] = __shfl(invq, g * 4 + jj);
#pragma unroll
    for (int db = 0; db < 4; ++db)
#pragma unroll
      for (int jj = 0; jj < 4; ++jj)
        Og[((size_t)b * 2048 + qw + qs * 16 + g * 4 + jj) * 1024 + hh * 64 +
           db * 16 + l4] = f2bf(o[qs][db][jj] * inv[jj]);
  }
#undef STAGE
}

// ---------------------------------------------------------------- launch
extern "C" void kernel_launch(void* const* d_in, const int* in_sizes, int n_in,
                              void* d_out, int out_size, void* d_ws, size_t ws_size,
                              hipStream_t stream) {
  const float* x = (const float*)d_in[0];
  const float* w_qkv = (const float*)d_in[1];
  const float* b_qkv = (const float*)d_in[2];
  const float* w_proj = (const float*)d_in[3];
  const float* b_proj = (const float*)d_in[4];
  float* out = (float*)d_out;

  char* p = (char*)d_ws;
  unsigned short* xb = (unsigned short*)p;     p += (size_t)8192 * 1024 * 2;
  unsigned short* wqkvb = (unsigned short*)p;  p += (size_t)3072 * 1024 * 2;
  unsigned short* wprojb = (unsigned short*)p; p += (size_t)1024 * 1024 * 2;
  unsigned short* qb = (unsigned short*)p;     p += (size_t)64 * 2048 * 64 * 2;
  unsigned short* kb = (unsigned short*)p;     p += (size_t)64 * 2048 * 64 * 2;
  _Float16* vtb = (_Float16*)p;                p += (size_t)64 * 64 * 2048 * 2;
  unsigned short* attnb = (unsigned short*)p;  p += (size_t)8192 * 1024 * 2;

  cvt_f32_bf16<<<dim3(8192), dim3(256), 0, stream>>>(x, xb, 8192 * 1024);
  cvt_f32_bf16<<<dim3(3072), dim3(256), 0, stream>>>(w_qkv, wqkvb, 3072 * 1024);
  cvt_f32_bf16<<<dim3(1024), dim3(256), 0, stream>>>(w_proj, wprojb, 1024 * 1024);

  gemm_bt<1><<<dim3(64 * 24), dim3(256), 0, stream>>>(
      xb, wqkvb, b_qkv, nullptr, qb, kb, vtb, 8192, 3072, 1024);

  attn_fwd<<<dim3(1024), dim3(256), 0, stream>>>(qb, kb, vtb, attnb);

  gemm_bt<0><<<dim3(64 * 8), dim3(256), 0, stream>>>(
      attnb, wprojb, b_proj, out, nullptr, nullptr, nullptr, 8192, 1024, 1024);
}